// Round 11
// baseline (39.437 us; speedup 1.0000x reference)
//
#include <hip/hip_runtime.h>
#include <hip/hip_bf16.h>

#define ALPHA 0.2f
#define NEGINF -9000000000000000.0f

typedef __attribute__((ext_vector_type(8))) short short8;
typedef __attribute__((ext_vector_type(4))) float f32x4;
typedef __attribute__((ext_vector_type(4))) int i32x4;
typedef __attribute__((ext_vector_type(4))) unsigned short u16x4;

static constexpr int NB = 4, NN = 1024, NF = 256, NH = 32;

__device__ __forceinline__ unsigned short f2bf(float x) {
  union { float f; unsigned u; } v; v.f = x;
  unsigned r = v.u + 0x7fffu + ((v.u >> 16) & 1u);
  return (unsigned short)(r >> 16);
}

// ---- Kernel A: W pack + wa1/wa2 + adj->bitmask (adj stream hides under W) --
__global__ __launch_bounds__(256) void prep_kernel(
    const float* __restrict__ W, const float* __restrict__ a,
    const int* __restrict__ adj, float* __restrict__ wa1,
    float* __restrict__ wa2, unsigned short* __restrict__ WTp,
    unsigned long long* __restrict__ adjm) {
  int k = blockIdx.x;     // 0..255
  int t = threadIdx.x;    // 0..255
  const int* ap = adj + ((size_t)(k * 16 + (t >> 4))) * NN + (t & 15) * 64;
  i32x4 av[16];
#pragma unroll
  for (int i = 0; i < 16; ++i) av[i] = *(const i32x4*)(ap + i * 4);

  float w = W[k * NF + t];
  WTp[(((k >> 3) * NF) + t) * 8 + (k & 7)] = f2bf(w);
  float p1 = w * a[t];
  float p2 = w * a[NF + t];
#pragma unroll
  for (int off = 32; off >= 1; off >>= 1) {
    p1 += __shfl_xor(p1, off);
    p2 += __shfl_xor(p2, off);
  }
  __shared__ float r1[4], r2[4];
  if ((t & 63) == 0) { r1[t >> 6] = p1; r2[t >> 6] = p2; }
  __syncthreads();
  if (t == 0) {
    wa1[k] = r1[0] + r1[1] + r1[2] + r1[3];
    wa2[k] = r2[0] + r2[1] + r2[2] + r2[3];
  }

  unsigned long long m = 0ull;
#pragma unroll
  for (int i = 0; i < 16; ++i)
#pragma unroll
    for (int u = 0; u < 4; ++u)
      m |= (unsigned long long)(av[i][u] > 0) << (i * 4 + u);
  adjm[(size_t)k * 256 + t] = m;
}

// ---- Kernel B: Wh = h@W (bf16 MFMA, packed for PV B-frags) + s1/s2 ----
__global__ __launch_bounds__(512) void wh_kernel(
    const float* __restrict__ h, const unsigned short* __restrict__ WTp,
    const float* __restrict__ wa1, const float* __restrict__ wa2,
    unsigned short* __restrict__ WhP, float* __restrict__ s1g,
    float* __restrict__ s2g) {
  __shared__ unsigned short hs[16 * 256];  // 8KB, XOR-swizzled
  int bid = blockIdx.x;
  int b = bid >> 6;
  int rb = (bid & 63) << 4;
  int t = threadIdx.x;
  {
    int row = t >> 5, c0 = (t & 31) * 8;
    const float* src = h + (size_t)(b * NN + rb + row) * NF + c0;
    f32x4 v0 = *(const f32x4*)src;
    f32x4 v1 = *(const f32x4*)(src + 4);
    unsigned short tmp[8] = {f2bf(v0.x), f2bf(v0.y), f2bf(v0.z), f2bf(v0.w),
                             f2bf(v1.x), f2bf(v1.y), f2bf(v1.z), f2bf(v1.w)};
    int off = row * 512 + ((c0 * 2) ^ ((row & 7) << 4));
    *(short8*)((char*)hs + off) = *(const short8*)tmp;
    f32x4 a10 = *(const f32x4*)(wa1 + c0);
    f32x4 a11 = *(const f32x4*)(wa1 + c0 + 4);
    f32x4 a20 = *(const f32x4*)(wa2 + c0);
    f32x4 a21 = *(const f32x4*)(wa2 + c0 + 4);
    float d1 = v0.x * a10.x + v0.y * a10.y + v0.z * a10.z + v0.w * a10.w +
               v1.x * a11.x + v1.y * a11.y + v1.z * a11.z + v1.w * a11.w;
    float d2 = v0.x * a20.x + v0.y * a20.y + v0.z * a20.z + v0.w * a20.w +
               v1.x * a21.x + v1.y * a21.y + v1.z * a21.z + v1.w * a21.w;
#pragma unroll
    for (int off2 = 16; off2 >= 1; off2 >>= 1) {
      d1 += __shfl_xor(d1, off2);
      d2 += __shfl_xor(d2, off2);
    }
    if ((t & 31) == 0) {
      s1g[b * NN + rb + row] = d1;
      s2g[b * NN + rb + row] = d2;
    }
  }
  __syncthreads();
  int wid = t >> 6, lane = t & 63;
  int fb = wid * 32;
  int rowa = lane & 15, kg = lane >> 4;
  f32x4 acc0 = {0.f, 0.f, 0.f, 0.f}, acc1 = {0.f, 0.f, 0.f, 0.f};
#pragma unroll
  for (int ks = 0; ks < 8; ++ks) {
    int k0 = ks * 32;
    short8 af = *(const short8*)((const char*)hs + rowa * 512 +
                                 ((2 * (k0 + kg * 8)) ^ ((rowa & 7) << 4)));
    int kc = ks * 4 + kg;
    short8 bf0 = *(const short8*)(WTp + ((kc * NF) + fb + (lane & 15)) * 8);
    short8 bf1 = *(const short8*)(WTp + ((kc * NF) + fb + 16 + (lane & 15)) * 8);
    acc0 = __builtin_amdgcn_mfma_f32_16x16x32_bf16(af, bf0, acc0, 0, 0, 0);
    acc1 = __builtin_amdgcn_mfma_f32_16x16x32_bf16(af, bf1, acc1, 0, 0, 0);
  }
#pragma unroll
  for (int r = 0; r < 4; ++r) {
    int jl = (lane >> 4) * 4 + r;
    int j = rb + jl;
    int base = ((b << 7) + (j >> 3)) * NF;
    WhP[(size_t)(base + fb + (lane & 15)) * 8 + (j & 7)] = f2bf(acc0[r]);
    WhP[(size_t)(base + fb + 16 + (lane & 15)) * 8 + (j & 7)] = f2bf(acc1[r]);
  }
}

// ---- Kernel C: scores + softmax + PV + ELU (R7 structure, mask-fed) ----
__global__ __launch_bounds__(1024) void attn_kernel(
    const float* __restrict__ mz, const unsigned long long* __restrict__ adjm,
    const unsigned short* __restrict__ WhP,
    const float* __restrict__ w1, const float* __restrict__ b1,
    const float* __restrict__ w2, const float* __restrict__ b2,
    const float* __restrict__ s1g, const float* __restrict__ s2g,
    float* __restrict__ out) {
  __shared__ unsigned short Pb[32 * 1024];
  __shared__ unsigned long long adjmsh[32][16];
  __shared__ float mzs[1024];
  __shared__ float s2s[1024];
  __shared__ float s1s[32];
  __shared__ float rinv[32];
  __shared__ float segsh[3];

  int bid0 = blockIdx.x;
  int bid = (bid0 & 7) * 16 + (bid0 >> 3);
  int b = bid >> 5;
  int rb = (bid & 31) << 5;
  int t = threadIdx.x;
  int wid = t >> 6, lane = t & 63;

  if (t < 512) {
    int r = t >> 4, sg = t & 15;
    adjmsh[r][sg] = adjm[(size_t)(b * NN + rb + r) * 16 + sg];
  }
  if (t < NH) {
    float w1h = w1[t], b1h = b1[t], w2h = w2[t];
    bool bp = (w1h != 0.f) && (b1h != 0.f) && ((b1h > 0.f) != (w1h > 0.f));
    bool act = (w1h + b1h) > 0.f;
    float cA = act ? w2h * w1h : 0.f;
    float cB = act ? w2h * b1h : 0.f;
    float nbp = bp ? 1.f : 0.f;
#pragma unroll
    for (int off = 16; off >= 1; off >>= 1) {
      cA += __shfl_xor(cA, off);
      cB += __shfl_xor(cB, off);
      nbp += __shfl_xor(nbp, off);
    }
    if (t == 0) {
      segsh[0] = (nbp == 0.f) ? 1.f : 0.f;
      segsh[1] = cA;
      segsh[2] = cB + b2[0];
    }
  }
  mzs[t] = mz[b * NN + t];
  s2s[t] = s2g[b * NN + t];
  if (t < 32) s1s[t] = s1g[b * NN + rb + t];
  __syncthreads();

  float segF = segsh[0], segA = segsh[1], segB = segsh[2];
  float b2v = b2[0];
  for (int rr = 0; rr < 2; ++rr) {
    int row = wid * 2 + rr;
    int ig = rb + row;
    float s1v = s1s[row];
    float mzi = mzs[ig];
    float e[16];
    if (segF != 0.f) {
#pragma unroll
      for (int c = 0; c < 4; ++c) {
        int j0 = c * 256 + lane * 4;
        unsigned nib =
            (unsigned)(adjmsh[row][c * 4 + (lane >> 4)] >> ((lane & 15) * 4)) &
            0xFu;
        f32x4 mzv = *(const f32x4*)(mzs + j0);
        f32x4 s2v = *(const f32x4*)(s2s + j0);
#pragma unroll
        for (int u = 0; u < 4; ++u) {
          float dd = fabsf(mzi - mzv[u]);
          float d = (ig == 0 || (j0 + u) == 0) ? 0.f : dd;
          float s = s1v + s2v[u];
          s = fmaxf(s, 0.f) + ALPHA * fminf(s, 0.f);
          float ee = s + fmaf(d, segA, segB);
          e[c * 4 + u] = (nib & (1u << u)) ? ee : NEGINF;
        }
      }
    } else {
#pragma unroll
      for (int c = 0; c < 4; ++c) {
        int j0 = c * 256 + lane * 4;
        unsigned nib =
            (unsigned)(adjmsh[row][c * 4 + (lane >> 4)] >> ((lane & 15) * 4)) &
            0xFu;
        f32x4 mzv = *(const f32x4*)(mzs + j0);
        f32x4 s2v = *(const f32x4*)(s2s + j0);
        float d[4], acc[4];
#pragma unroll
        for (int u = 0; u < 4; ++u) {
          float dd = fabsf(mzi - mzv[u]);
          d[u] = (ig == 0 || (j0 + u) == 0) ? 0.f : dd;
          acc[u] = b2v;
        }
#pragma unroll 1
        for (int hh = 0; hh < NH; ++hh) {
          float w1h = w1[hh], b1h = b1[hh], w2h = w2[hh];
#pragma unroll
          for (int u = 0; u < 4; ++u)
            acc[u] += fmaxf(d[u] * w1h + b1h, 0.f) * w2h;
        }
#pragma unroll
        for (int u = 0; u < 4; ++u) {
          float s = s1v + s2v[u];
          s = s > 0.f ? s : ALPHA * s;
          e[c * 4 + u] = (nib & (1u << u)) ? (s + acc[u]) : NEGINF;
        }
      }
    }
    float m = -3.0e38f;
#pragma unroll
    for (int q = 0; q < 16; ++q) m = fmaxf(m, e[q]);
#pragma unroll
    for (int off = 32; off >= 1; off >>= 1) m = fmaxf(m, __shfl_xor(m, off));
    float sum = 0.f;
#pragma unroll
    for (int q = 0; q < 16; ++q) {
      e[q] = __expf(e[q] - m);
      sum += e[q];
    }
#pragma unroll
    for (int off = 32; off >= 1; off >>= 1) sum += __shfl_xor(sum, off);
#pragma unroll
    for (int c = 0; c < 4; ++c) {
      u16x4 pk = {f2bf(e[c * 4 + 0]), f2bf(e[c * 4 + 1]),
                  f2bf(e[c * 4 + 2]), f2bf(e[c * 4 + 3])};
      int byteoff = row * 2048 + ((512 * c + 8 * lane) ^ ((row & 7) << 4));
      *(u16x4*)((char*)Pb + byteoff) = pk;
    }
    if (lane == 0) rinv[row] = 1.0f / sum;
  }
  __syncthreads();

  {
    int fb = wid * 16;
    int fl = lane & 15, kg = lane >> 4;
    const unsigned short* whb = WhP + (((size_t)b) << 7) * NF * 8;
    f32x4 acc0 = {0.f, 0.f, 0.f, 0.f}, acc1 = {0.f, 0.f, 0.f, 0.f};
    int abase = fl * 2048;
#pragma unroll 4
    for (int ks = 0; ks < 32; ++ks) {
      int k0 = ks * 32;
      int kc = ks * 4 + kg;
      short8 bf = *(const short8*)(whb + (size_t)((kc * NF) + fb + fl) * 8);
      int aoff = (2 * (k0 + kg * 8)) ^ ((fl & 7) << 4);
      short8 af0 = *(const short8*)((const char*)Pb + abase + aoff);
      short8 af1 = *(const short8*)((const char*)Pb + abase + 32768 + aoff);
      acc0 = __builtin_amdgcn_mfma_f32_16x16x32_bf16(af0, bf, acc0, 0, 0, 0);
      acc1 = __builtin_amdgcn_mfma_f32_16x16x32_bf16(af1, bf, acc1, 0, 0, 0);
    }
#pragma unroll
    for (int r = 0; r < 4; ++r) {
      int il0 = (lane >> 4) * 4 + r;
      int il1 = il0 + 16;
      float x0 = acc0[r] * rinv[il0];
      float x1 = acc1[r] * rinv[il1];
      x0 = x0 > 0.f ? x0 : (__expf(x0) - 1.f);
      x1 = x1 > 0.f ? x1 : (__expf(x1) - 1.f);
      out[(size_t)(b * NN + rb + il0) * NF + fb + fl] = x0;
      out[(size_t)(b * NN + rb + il1) * NF + fb + fl] = x1;
    }
  }
}

extern "C" void kernel_launch(void* const* d_in, const int* in_sizes, int n_in,
                              void* d_out, int out_size, void* d_ws, size_t ws_size,
                              hipStream_t stream) {
  const float* h   = (const float*)d_in[0];
  const float* mz  = (const float*)d_in[1];
  const float* W   = (const float*)d_in[2];
  const float* a   = (const float*)d_in[3];
  const float* w1  = (const float*)d_in[4];
  const float* b1  = (const float*)d_in[5];
  const float* w2  = (const float*)d_in[6];
  const float* b2  = (const float*)d_in[7];
  const int*   adj = (const int*)d_in[8];
  float* out = (float*)d_out;

  unsigned short* WTp = (unsigned short*)d_ws;            // 128KB
  unsigned short* WhP = WTp + 65536;                      // 2MB
  float* wa1 = (float*)(WhP + (size_t)NB * NN * NF);
  float* wa2 = wa1 + 256;
  float* s1g = wa2 + 256;
  float* s2g = s1g + NB * NN;
  unsigned long long* adjm = (unsigned long long*)(s2g + NB * NN);  // 512KB

  prep_kernel<<<dim3(256), dim3(256), 0, stream>>>(W, a, adj, wa1, wa2, WTp,
                                                   adjm);
  wh_kernel<<<dim3(256), dim3(512), 0, stream>>>(h, WTp, wa1, wa2, WhP, s1g, s2g);
  // DIAGNOSTIC: attn launched twice (idempotent — identical out rewrite).
  // dur_us - 27.3 = attn marginal (warm) cost + 1 dispatch boundary.
  attn_kernel<<<dim3(128), dim3(1024), 0, stream>>>(mz, adjm, WhP, w1, b1, w2,
                                                    b2, s1g, s2g, out);
  attn_kernel<<<dim3(128), dim3(1024), 0, stream>>>(mz, adjm, WhP, w1, b1, w2,
                                                    b2, s1g, s2g, out);
}

// Round 12
// 26.957 us; speedup vs baseline: 1.4629x; 1.4629x over previous
//
#include <hip/hip_runtime.h>
#include <hip/hip_bf16.h>

#define ALPHA 0.2f
#define NEGINF -9000000000000000.0f

typedef __attribute__((ext_vector_type(8))) short short8;
typedef __attribute__((ext_vector_type(4))) float f32x4;
typedef __attribute__((ext_vector_type(4))) int i32x4;
typedef __attribute__((ext_vector_type(4))) unsigned short u16x4;

static constexpr int NB = 4, NN = 1024, NF = 256, NH = 32;

__device__ __forceinline__ unsigned short f2bf(float x) {
  union { float f; unsigned u; } v; v.f = x;
  unsigned r = v.u + 0x7fffu + ((v.u >> 16) & 1u);
  return (unsigned short)(r >> 16);
}

// ---- Kernel A: W pack + wa1/wa2 + adj->bitmask (adj stream hides under W) --
__global__ __launch_bounds__(256) void prep_kernel(
    const float* __restrict__ W, const float* __restrict__ a,
    const int* __restrict__ adj, float* __restrict__ wa1,
    float* __restrict__ wa2, unsigned short* __restrict__ WTp,
    unsigned long long* __restrict__ adjm) {
  int k = blockIdx.x;     // 0..255
  int t = threadIdx.x;    // 0..255
  const int* ap = adj + ((size_t)(k * 16 + (t >> 4))) * NN + (t & 15) * 64;
  i32x4 av[16];
#pragma unroll
  for (int i = 0; i < 16; ++i) av[i] = *(const i32x4*)(ap + i * 4);

  float w = W[k * NF + t];
  WTp[(((k >> 3) * NF) + t) * 8 + (k & 7)] = f2bf(w);
  float p1 = w * a[t];
  float p2 = w * a[NF + t];
#pragma unroll
  for (int off = 32; off >= 1; off >>= 1) {
    p1 += __shfl_xor(p1, off);
    p2 += __shfl_xor(p2, off);
  }
  __shared__ float r1[4], r2[4];
  if ((t & 63) == 0) { r1[t >> 6] = p1; r2[t >> 6] = p2; }
  __syncthreads();
  if (t == 0) {
    wa1[k] = r1[0] + r1[1] + r1[2] + r1[3];
    wa2[k] = r2[0] + r2[1] + r2[2] + r2[3];
  }

  unsigned long long m = 0ull;
#pragma unroll
  for (int i = 0; i < 16; ++i)
#pragma unroll
    for (int u = 0; u < 4; ++u)
      m |= (unsigned long long)(av[i][u] > 0) << (i * 4 + u);
  adjm[(size_t)k * 256 + t] = m;
}

// ---- Kernel B: Wh = h@W (bf16 MFMA, packed for PV B-frags) + s1/s2 ----
__global__ __launch_bounds__(512) void wh_kernel(
    const float* __restrict__ h, const unsigned short* __restrict__ WTp,
    const float* __restrict__ wa1, const float* __restrict__ wa2,
    unsigned short* __restrict__ WhP, float* __restrict__ s1g,
    float* __restrict__ s2g) {
  __shared__ unsigned short hs[16 * 256];  // 8KB, XOR-swizzled
  int bid = blockIdx.x;
  int b = bid >> 6;
  int rb = (bid & 63) << 4;
  int t = threadIdx.x;
  {
    int row = t >> 5, c0 = (t & 31) * 8;
    const float* src = h + (size_t)(b * NN + rb + row) * NF + c0;
    f32x4 v0 = *(const f32x4*)src;
    f32x4 v1 = *(const f32x4*)(src + 4);
    unsigned short tmp[8] = {f2bf(v0.x), f2bf(v0.y), f2bf(v0.z), f2bf(v0.w),
                             f2bf(v1.x), f2bf(v1.y), f2bf(v1.z), f2bf(v1.w)};
    int off = row * 512 + ((c0 * 2) ^ ((row & 7) << 4));
    *(short8*)((char*)hs + off) = *(const short8*)tmp;
    f32x4 a10 = *(const f32x4*)(wa1 + c0);
    f32x4 a11 = *(const f32x4*)(wa1 + c0 + 4);
    f32x4 a20 = *(const f32x4*)(wa2 + c0);
    f32x4 a21 = *(const f32x4*)(wa2 + c0 + 4);
    float d1 = v0.x * a10.x + v0.y * a10.y + v0.z * a10.z + v0.w * a10.w +
               v1.x * a11.x + v1.y * a11.y + v1.z * a11.z + v1.w * a11.w;
    float d2 = v0.x * a20.x + v0.y * a20.y + v0.z * a20.z + v0.w * a20.w +
               v1.x * a21.x + v1.y * a21.y + v1.z * a21.z + v1.w * a21.w;
#pragma unroll
    for (int off2 = 16; off2 >= 1; off2 >>= 1) {
      d1 += __shfl_xor(d1, off2);
      d2 += __shfl_xor(d2, off2);
    }
    if ((t & 31) == 0) {
      s1g[b * NN + rb + row] = d1;
      s2g[b * NN + rb + row] = d2;
    }
  }
  __syncthreads();
  int wid = t >> 6, lane = t & 63;
  int fb = wid * 32;
  int rowa = lane & 15, kg = lane >> 4;
  f32x4 acc0 = {0.f, 0.f, 0.f, 0.f}, acc1 = {0.f, 0.f, 0.f, 0.f};
#pragma unroll
  for (int ks = 0; ks < 8; ++ks) {
    int k0 = ks * 32;
    short8 af = *(const short8*)((const char*)hs + rowa * 512 +
                                 ((2 * (k0 + kg * 8)) ^ ((rowa & 7) << 4)));
    int kc = ks * 4 + kg;
    short8 bf0 = *(const short8*)(WTp + ((kc * NF) + fb + (lane & 15)) * 8);
    short8 bf1 = *(const short8*)(WTp + ((kc * NF) + fb + 16 + (lane & 15)) * 8);
    acc0 = __builtin_amdgcn_mfma_f32_16x16x32_bf16(af, bf0, acc0, 0, 0, 0);
    acc1 = __builtin_amdgcn_mfma_f32_16x16x32_bf16(af, bf1, acc1, 0, 0, 0);
  }
#pragma unroll
  for (int r = 0; r < 4; ++r) {
    int jl = (lane >> 4) * 4 + r;
    int j = rb + jl;
    int base = ((b << 7) + (j >> 3)) * NF;
    WhP[(size_t)(base + fb + (lane & 15)) * 8 + (j & 7)] = f2bf(acc0[r]);
    WhP[(size_t)(base + fb + 16 + (lane & 15)) * 8 + (j & 7)] = f2bf(acc1[r]);
  }
}

// ---- Kernel C: scores + softmax + PV + ELU (R10 structure + B-frag
// prefetch: PV's WhP loads issued BEFORE the scores phase so the L2/L3
// stream hides under scores VALU) ----
__global__ __launch_bounds__(1024) void attn_kernel(
    const float* __restrict__ mz, const unsigned long long* __restrict__ adjm,
    const unsigned short* __restrict__ WhP,
    const float* __restrict__ w1, const float* __restrict__ b1,
    const float* __restrict__ w2, const float* __restrict__ b2,
    const float* __restrict__ s1g, const float* __restrict__ s2g,
    float* __restrict__ out) {
  __shared__ unsigned short Pb[32 * 1024];
  __shared__ unsigned long long adjmsh[32][16];
  __shared__ float mzs[1024];
  __shared__ float s2s[1024];
  __shared__ float s1s[32];
  __shared__ float rinv[32];
  __shared__ float segsh[3];

  int bid0 = blockIdx.x;
  int bid = (bid0 & 7) * 16 + (bid0 >> 3);
  int b = bid >> 5;
  int rb = (bid & 31) << 5;
  int t = threadIdx.x;
  int wid = t >> 6, lane = t & 63;

  // PV geometry + B-frag prefetch (independent of scores; issue early).
  int fb = wid * 16;
  int fl = lane & 15, kg = lane >> 4;
  const unsigned short* whb = WhP + (((size_t)b) << 7) * NF * 8;
  short8 pf[36];  // constant-indexed only -> stays in VGPRs
#pragma unroll
  for (int ks = 0; ks < 8; ++ks)
    pf[ks] =
        *(const short8*)(whb + (size_t)(((ks * 4 + kg) * NF) + fb + fl) * 8);

  if (t < 512) {
    int r = t >> 4, sg = t & 15;
    adjmsh[r][sg] = adjm[(size_t)(b * NN + rb + r) * 16 + sg];
  }
  if (t < NH) {
    float w1h = w1[t], b1h = b1[t], w2h = w2[t];
    bool bp = (w1h != 0.f) && (b1h != 0.f) && ((b1h > 0.f) != (w1h > 0.f));
    bool act = (w1h + b1h) > 0.f;
    float cA = act ? w2h * w1h : 0.f;
    float cB = act ? w2h * b1h : 0.f;
    float nbp = bp ? 1.f : 0.f;
#pragma unroll
    for (int off = 16; off >= 1; off >>= 1) {
      cA += __shfl_xor(cA, off);
      cB += __shfl_xor(cB, off);
      nbp += __shfl_xor(nbp, off);
    }
    if (t == 0) {
      segsh[0] = (nbp == 0.f) ? 1.f : 0.f;
      segsh[1] = cA;
      segsh[2] = cB + b2[0];
    }
  }
  mzs[t] = mz[b * NN + t];
  s2s[t] = s2g[b * NN + t];
  if (t < 32) s1s[t] = s1g[b * NN + rb + t];
  __syncthreads();

  float segF = segsh[0], segA = segsh[1], segB = segsh[2];
  float b2v = b2[0];
  for (int rr = 0; rr < 2; ++rr) {
    int row = wid * 2 + rr;
    int ig = rb + row;
    float s1v = s1s[row];
    float mzi = mzs[ig];
    float e[16];
    if (segF != 0.f) {
#pragma unroll
      for (int c = 0; c < 4; ++c) {
        int j0 = c * 256 + lane * 4;
        unsigned nib =
            (unsigned)(adjmsh[row][c * 4 + (lane >> 4)] >> ((lane & 15) * 4)) &
            0xFu;
        f32x4 mzv = *(const f32x4*)(mzs + j0);
        f32x4 s2v = *(const f32x4*)(s2s + j0);
#pragma unroll
        for (int u = 0; u < 4; ++u) {
          float dd = fabsf(mzi - mzv[u]);
          float d = (ig == 0 || (j0 + u) == 0) ? 0.f : dd;
          float s = s1v + s2v[u];
          s = fmaxf(s, 0.f) + ALPHA * fminf(s, 0.f);
          float ee = s + fmaf(d, segA, segB);
          e[c * 4 + u] = (nib & (1u << u)) ? ee : NEGINF;
        }
      }
    } else {
#pragma unroll
      for (int c = 0; c < 4; ++c) {
        int j0 = c * 256 + lane * 4;
        unsigned nib =
            (unsigned)(adjmsh[row][c * 4 + (lane >> 4)] >> ((lane & 15) * 4)) &
            0xFu;
        f32x4 mzv = *(const f32x4*)(mzs + j0);
        f32x4 s2v = *(const f32x4*)(s2s + j0);
        float d[4], acc[4];
#pragma unroll
        for (int u = 0; u < 4; ++u) {
          float dd = fabsf(mzi - mzv[u]);
          d[u] = (ig == 0 || (j0 + u) == 0) ? 0.f : dd;
          acc[u] = b2v;
        }
#pragma unroll 1
        for (int hh = 0; hh < NH; ++hh) {
          float w1h = w1[hh], b1h = b1[hh], w2h = w2[hh];
#pragma unroll
          for (int u = 0; u < 4; ++u)
            acc[u] += fmaxf(d[u] * w1h + b1h, 0.f) * w2h;
        }
#pragma unroll
        for (int u = 0; u < 4; ++u) {
          float s = s1v + s2v[u];
          s = s > 0.f ? s : ALPHA * s;
          e[c * 4 + u] = (nib & (1u << u)) ? (s + acc[u]) : NEGINF;
        }
      }
    }
    float m = -3.0e38f;
#pragma unroll
    for (int q = 0; q < 16; ++q) m = fmaxf(m, e[q]);
#pragma unroll
    for (int off = 32; off >= 1; off >>= 1) m = fmaxf(m, __shfl_xor(m, off));
    float sum = 0.f;
#pragma unroll
    for (int q = 0; q < 16; ++q) {
      e[q] = __expf(e[q] - m);
      sum += e[q];
    }
#pragma unroll
    for (int off = 32; off >= 1; off >>= 1) sum += __shfl_xor(sum, off);
#pragma unroll
    for (int c = 0; c < 4; ++c) {
      u16x4 pk = {f2bf(e[c * 4 + 0]), f2bf(e[c * 4 + 1]),
                  f2bf(e[c * 4 + 2]), f2bf(e[c * 4 + 3])};
      int byteoff = row * 2048 + ((512 * c + 8 * lane) ^ ((row & 7) << 4));
      *(u16x4*)((char*)Pb + byteoff) = pk;
    }
    if (lane == 0) rinv[row] = 1.0f / sum;
  }
  __syncthreads();

  // PV: fully-unrolled with 8-deep rolling B-frag prefetch (pf[] constant-
  // indexed -> registers). D[i][f] = sum_j P[i][j]*Wh[j][f].
  {
    f32x4 acc0 = {0.f, 0.f, 0.f, 0.f}, acc1 = {0.f, 0.f, 0.f, 0.f};
    int abase = fl * 2048;
#pragma unroll
    for (int ks = 0; ks < 32; ++ks) {
      if (ks + 8 < 32)
        pf[ks + 8] = *(const short8*)(
            whb + (size_t)((((ks + 8) * 4 + kg) * NF) + fb + fl) * 8);
      int aoff = (2 * (ks * 32 + kg * 8)) ^ ((fl & 7) << 4);
      short8 af0 = *(const short8*)((const char*)Pb + abase + aoff);
      short8 af1 = *(const short8*)((const char*)Pb + abase + 32768 + aoff);
      acc0 = __builtin_amdgcn_mfma_f32_16x16x32_bf16(af0, pf[ks], acc0, 0, 0, 0);
      acc1 = __builtin_amdgcn_mfma_f32_16x16x32_bf16(af1, pf[ks], acc1, 0, 0, 0);
    }
#pragma unroll
    for (int r = 0; r < 4; ++r) {
      int il0 = (lane >> 4) * 4 + r;
      int il1 = il0 + 16;
      float x0 = acc0[r] * rinv[il0];
      float x1 = acc1[r] * rinv[il1];
      x0 = x0 > 0.f ? x0 : (__expf(x0) - 1.f);
      x1 = x1 > 0.f ? x1 : (__expf(x1) - 1.f);
      out[(size_t)(b * NN + rb + il0) * NF + fb + fl] = x0;
      out[(size_t)(b * NN + rb + il1) * NF + fb + fl] = x1;
    }
  }
}

extern "C" void kernel_launch(void* const* d_in, const int* in_sizes, int n_in,
                              void* d_out, int out_size, void* d_ws, size_t ws_size,
                              hipStream_t stream) {
  const float* h   = (const float*)d_in[0];
  const float* mz  = (const float*)d_in[1];
  const float* W   = (const float*)d_in[2];
  const float* a   = (const float*)d_in[3];
  const float* w1  = (const float*)d_in[4];
  const float* b1  = (const float*)d_in[5];
  const float* w2  = (const float*)d_in[6];
  const float* b2  = (const float*)d_in[7];
  const int*   adj = (const int*)d_in[8];
  float* out = (float*)d_out;

  unsigned short* WTp = (unsigned short*)d_ws;            // 128KB
  unsigned short* WhP = WTp + 65536;                      // 2MB
  float* wa1 = (float*)(WhP + (size_t)NB * NN * NF);
  float* wa2 = wa1 + 256;
  float* s1g = wa2 + 256;
  float* s2g = s1g + NB * NN;
  unsigned long long* adjm = (unsigned long long*)(s2g + NB * NN);  // 512KB

  prep_kernel<<<dim3(256), dim3(256), 0, stream>>>(W, a, adj, wa1, wa2, WTp,
                                                   adjm);
  wh_kernel<<<dim3(256), dim3(512), 0, stream>>>(h, WTp, wa1, wa2, WhP, s1g, s2g);
  attn_kernel<<<dim3(128), dim3(1024), 0, stream>>>(mz, adjm, WhP, w1, b1, w2,
                                                    b2, s1g, s2g, out);
}

// Round 13
// 26.339 us; speedup vs baseline: 1.4973x; 1.0235x over previous
//
#include <hip/hip_runtime.h>
#include <hip/hip_bf16.h>

#define ALPHA 0.2f
#define NEGINF -9000000000000000.0f

typedef __attribute__((ext_vector_type(8))) short short8;
typedef __attribute__((ext_vector_type(4))) float f32x4;
typedef __attribute__((ext_vector_type(4))) int i32x4;
typedef __attribute__((ext_vector_type(4))) unsigned short u16x4;

static constexpr int NB = 4, NN = 1024, NF = 256, NH = 32;

__device__ __forceinline__ unsigned short f2bf(float x) {
  union { float f; unsigned u; } v; v.f = x;
  unsigned r = v.u + 0x7fffu + ((v.u >> 16) & 1u);
  return (unsigned short)(r >> 16);
}

// ---- Kernel A: W pack + wa1/wa2 + adj->bitmask (adj stream hides under W) --
__global__ __launch_bounds__(256) void prep_kernel(
    const float* __restrict__ W, const float* __restrict__ a,
    const int* __restrict__ adj, float* __restrict__ wa1,
    float* __restrict__ wa2, unsigned short* __restrict__ WTp,
    unsigned long long* __restrict__ adjm) {
  int k = blockIdx.x;     // 0..255
  int t = threadIdx.x;    // 0..255
  const int* ap = adj + ((size_t)(k * 16 + (t >> 4))) * NN + (t & 15) * 64;
  i32x4 av[16];
#pragma unroll
  for (int i = 0; i < 16; ++i) av[i] = *(const i32x4*)(ap + i * 4);

  float w = W[k * NF + t];
  WTp[(((k >> 3) * NF) + t) * 8 + (k & 7)] = f2bf(w);
  float p1 = w * a[t];
  float p2 = w * a[NF + t];
#pragma unroll
  for (int off = 32; off >= 1; off >>= 1) {
    p1 += __shfl_xor(p1, off);
    p2 += __shfl_xor(p2, off);
  }
  __shared__ float r1[4], r2[4];
  if ((t & 63) == 0) { r1[t >> 6] = p1; r2[t >> 6] = p2; }
  __syncthreads();
  if (t == 0) {
    wa1[k] = r1[0] + r1[1] + r1[2] + r1[3];
    wa2[k] = r2[0] + r2[1] + r2[2] + r2[3];
  }

  unsigned long long m = 0ull;
#pragma unroll
  for (int i = 0; i < 16; ++i)
#pragma unroll
    for (int u = 0; u < 4; ++u)
      m |= (unsigned long long)(av[i][u] > 0) << (i * 4 + u);
  adjm[(size_t)k * 256 + t] = m;
}

// ---- Kernel B: Wh = h@W (bf16 MFMA, packed for PV B-frags) + s1/s2 ----
__global__ __launch_bounds__(512) void wh_kernel(
    const float* __restrict__ h, const unsigned short* __restrict__ WTp,
    const float* __restrict__ wa1, const float* __restrict__ wa2,
    unsigned short* __restrict__ WhP, float* __restrict__ s1g,
    float* __restrict__ s2g) {
  __shared__ unsigned short hs[16 * 256];  // 8KB, XOR-swizzled
  int bid = blockIdx.x;
  int b = bid >> 6;
  int rb = (bid & 63) << 4;
  int t = threadIdx.x;
  {
    int row = t >> 5, c0 = (t & 31) * 8;
    const float* src = h + (size_t)(b * NN + rb + row) * NF + c0;
    f32x4 v0 = *(const f32x4*)src;
    f32x4 v1 = *(const f32x4*)(src + 4);
    unsigned short tmp[8] = {f2bf(v0.x), f2bf(v0.y), f2bf(v0.z), f2bf(v0.w),
                             f2bf(v1.x), f2bf(v1.y), f2bf(v1.z), f2bf(v1.w)};
    int off = row * 512 + ((c0 * 2) ^ ((row & 7) << 4));
    *(short8*)((char*)hs + off) = *(const short8*)tmp;
    f32x4 a10 = *(const f32x4*)(wa1 + c0);
    f32x4 a11 = *(const f32x4*)(wa1 + c0 + 4);
    f32x4 a20 = *(const f32x4*)(wa2 + c0);
    f32x4 a21 = *(const f32x4*)(wa2 + c0 + 4);
    float d1 = v0.x * a10.x + v0.y * a10.y + v0.z * a10.z + v0.w * a10.w +
               v1.x * a11.x + v1.y * a11.y + v1.z * a11.z + v1.w * a11.w;
    float d2 = v0.x * a20.x + v0.y * a20.y + v0.z * a20.z + v0.w * a20.w +
               v1.x * a21.x + v1.y * a21.y + v1.z * a21.z + v1.w * a21.w;
#pragma unroll
    for (int off2 = 16; off2 >= 1; off2 >>= 1) {
      d1 += __shfl_xor(d1, off2);
      d2 += __shfl_xor(d2, off2);
    }
    if ((t & 31) == 0) {
      s1g[b * NN + rb + row] = d1;
      s2g[b * NN + rb + row] = d2;
    }
  }
  __syncthreads();
  int wid = t >> 6, lane = t & 63;
  int fb = wid * 32;
  int rowa = lane & 15, kg = lane >> 4;
  f32x4 acc0 = {0.f, 0.f, 0.f, 0.f}, acc1 = {0.f, 0.f, 0.f, 0.f};
#pragma unroll
  for (int ks = 0; ks < 8; ++ks) {
    int k0 = ks * 32;
    short8 af = *(const short8*)((const char*)hs + rowa * 512 +
                                 ((2 * (k0 + kg * 8)) ^ ((rowa & 7) << 4)));
    int kc = ks * 4 + kg;
    short8 bf0 = *(const short8*)(WTp + ((kc * NF) + fb + (lane & 15)) * 8);
    short8 bf1 = *(const short8*)(WTp + ((kc * NF) + fb + 16 + (lane & 15)) * 8);
    acc0 = __builtin_amdgcn_mfma_f32_16x16x32_bf16(af, bf0, acc0, 0, 0, 0);
    acc1 = __builtin_amdgcn_mfma_f32_16x16x32_bf16(af, bf1, acc1, 0, 0, 0);
  }
#pragma unroll
  for (int r = 0; r < 4; ++r) {
    int jl = (lane >> 4) * 4 + r;
    int j = rb + jl;
    int base = ((b << 7) + (j >> 3)) * NF;
    WhP[(size_t)(base + fb + (lane & 15)) * 8 + (j & 7)] = f2bf(acc0[r]);
    WhP[(size_t)(base + fb + 16 + (lane & 15)) * 8 + (j & 7)] = f2bf(acc1[r]);
  }
}

// ---- Kernel C: scores + softmax + PV + ELU ----
// 256 blocks x 512 threads: each block = 32 rows x 128 f-cols (f-half split).
// All 256 CUs active; per-block WhP read halves to 256KB (total 64MB, same).
// Scores recomputed per f-half (cheap VALU, now spread over 2x CUs).
__global__ __launch_bounds__(512) void attn_kernel(
    const float* __restrict__ mz, const unsigned long long* __restrict__ adjm,
    const unsigned short* __restrict__ WhP,
    const float* __restrict__ w1, const float* __restrict__ b1,
    const float* __restrict__ w2, const float* __restrict__ b2,
    const float* __restrict__ s1g, const float* __restrict__ s2g,
    float* __restrict__ out) {
  __shared__ unsigned short Pb[32 * 1024];       // 64KB XOR-swizzled bf16 P
  __shared__ unsigned long long adjmsh[32][16];  // 4KB bitmask
  __shared__ float mzs[1024];
  __shared__ float s2s[1024];
  __shared__ float s1s[32];
  __shared__ float rinv[32];
  __shared__ float segsh[3];

  int bid0 = blockIdx.x;  // 0..255
  // XCD-aware bijective swizzle (nwg=256 % 8 == 0)
  int bid = (bid0 & 7) * 32 + (bid0 >> 3);
  int b = bid >> 6;
  int rg = (bid >> 1) & 31;  // 32-row group within batch
  int fh = bid & 1;          // feature half (0..1)
  int rb = rg << 5;
  int fbw_base = fh << 7;
  int t = threadIdx.x;
  int wid = t >> 6, lane = t & 63;  // wid 0..7

  // PV geometry + B-frag prefetch (independent of scores; issue early).
  int fbw = fbw_base + wid * 16;  // this wave's 16 f-cols (global)
  int fl = lane & 15, kg = lane >> 4;
  const unsigned short* whb = WhP + (((size_t)b) << 7) * NF * 8;
  short8 pf[36];  // constant-indexed only -> stays in VGPRs
#pragma unroll
  for (int ks = 0; ks < 8; ++ks)
    pf[ks] =
        *(const short8*)(whb + (size_t)(((ks * 4 + kg) * NF) + fbw + fl) * 8);

  if (t < 512) {
    int r = t >> 4, sg = t & 15;
    adjmsh[r][sg] = adjm[(size_t)(b * NN + rb + r) * 16 + sg];
  }
  if (t < NH) {
    float w1h = w1[t], b1h = b1[t], w2h = w2[t];
    bool bp = (w1h != 0.f) && (b1h != 0.f) && ((b1h > 0.f) != (w1h > 0.f));
    bool act = (w1h + b1h) > 0.f;
    float cA = act ? w2h * w1h : 0.f;
    float cB = act ? w2h * b1h : 0.f;
    float nbp = bp ? 1.f : 0.f;
#pragma unroll
    for (int off = 16; off >= 1; off >>= 1) {
      cA += __shfl_xor(cA, off);
      cB += __shfl_xor(cB, off);
      nbp += __shfl_xor(nbp, off);
    }
    if (t == 0) {
      segsh[0] = (nbp == 0.f) ? 1.f : 0.f;
      segsh[1] = cA;
      segsh[2] = cB + b2[0];
    }
  }
  for (int i = t; i < NN; i += 512) {
    mzs[i] = mz[b * NN + i];
    s2s[i] = s2g[b * NN + i];
  }
  if (t < 32) s1s[t] = s1g[b * NN + rb + t];
  __syncthreads();

  float segF = segsh[0], segA = segsh[1], segB = segsh[2];
  float b2v = b2[0];
  for (int rr = 0; rr < 4; ++rr) {
    int row = wid * 4 + rr;  // 0..31; this wave owns this row entirely
    int ig = rb + row;
    float s1v = s1s[row];
    float mzi = mzs[ig];
    float e[16];
    if (segF != 0.f) {
#pragma unroll
      for (int c = 0; c < 4; ++c) {
        int j0 = c * 256 + lane * 4;
        unsigned nib =
            (unsigned)(adjmsh[row][c * 4 + (lane >> 4)] >> ((lane & 15) * 4)) &
            0xFu;
        f32x4 mzv = *(const f32x4*)(mzs + j0);
        f32x4 s2v = *(const f32x4*)(s2s + j0);
#pragma unroll
        for (int u = 0; u < 4; ++u) {
          float dd = fabsf(mzi - mzv[u]);
          float d = (ig == 0 || (j0 + u) == 0) ? 0.f : dd;
          float s = s1v + s2v[u];
          s = fmaxf(s, 0.f) + ALPHA * fminf(s, 0.f);
          float ee = s + fmaf(d, segA, segB);
          e[c * 4 + u] = (nib & (1u << u)) ? ee : NEGINF;
        }
      }
    } else {
#pragma unroll
      for (int c = 0; c < 4; ++c) {
        int j0 = c * 256 + lane * 4;
        unsigned nib =
            (unsigned)(adjmsh[row][c * 4 + (lane >> 4)] >> ((lane & 15) * 4)) &
            0xFu;
        f32x4 mzv = *(const f32x4*)(mzs + j0);
        f32x4 s2v = *(const f32x4*)(s2s + j0);
        float d[4], acc[4];
#pragma unroll
        for (int u = 0; u < 4; ++u) {
          float dd = fabsf(mzi - mzv[u]);
          d[u] = (ig == 0 || (j0 + u) == 0) ? 0.f : dd;
          acc[u] = b2v;
        }
#pragma unroll 1
        for (int hh = 0; hh < NH; ++hh) {
          float w1h = w1[hh], b1h = b1[hh], w2h = w2[hh];
#pragma unroll
          for (int u = 0; u < 4; ++u)
            acc[u] += fmaxf(d[u] * w1h + b1h, 0.f) * w2h;
        }
#pragma unroll
        for (int u = 0; u < 4; ++u) {
          float s = s1v + s2v[u];
          s = s > 0.f ? s : ALPHA * s;
          e[c * 4 + u] = (nib & (1u << u)) ? (s + acc[u]) : NEGINF;
        }
      }
    }
    float m = -3.0e38f;
#pragma unroll
    for (int q = 0; q < 16; ++q) m = fmaxf(m, e[q]);
#pragma unroll
    for (int off = 32; off >= 1; off >>= 1) m = fmaxf(m, __shfl_xor(m, off));
    float sum = 0.f;
#pragma unroll
    for (int q = 0; q < 16; ++q) {
      e[q] = __expf(e[q] - m);
      sum += e[q];
    }
#pragma unroll
    for (int off = 32; off >= 1; off >>= 1) sum += __shfl_xor(sum, off);
#pragma unroll
    for (int c = 0; c < 4; ++c) {
      u16x4 pk = {f2bf(e[c * 4 + 0]), f2bf(e[c * 4 + 1]),
                  f2bf(e[c * 4 + 2]), f2bf(e[c * 4 + 3])};
      int byteoff = row * 2048 + ((512 * c + 8 * lane) ^ ((row & 7) << 4));
      *(u16x4*)((char*)Pb + byteoff) = pk;
    }
    if (lane == 0) rinv[row] = 1.0f / sum;
  }
  __syncthreads();

  // PV: fully-unrolled, 8-deep rolling B-frag prefetch. Per wave: 16 f-cols
  // (fbw..fbw+15) x 2 row-tiles (0-15, 16-31).
  {
    f32x4 acc0 = {0.f, 0.f, 0.f, 0.f}, acc1 = {0.f, 0.f, 0.f, 0.f};
    int abase = fl * 2048;
#pragma unroll
    for (int ks = 0; ks < 32; ++ks) {
      if (ks + 8 < 32)
        pf[ks + 8] = *(const short8*)(
            whb + (size_t)((((ks + 8) * 4 + kg) * NF) + fbw + fl) * 8);
      int aoff = (2 * (ks * 32 + kg * 8)) ^ ((fl & 7) << 4);
      short8 af0 = *(const short8*)((const char*)Pb + abase + aoff);
      short8 af1 = *(const short8*)((const char*)Pb + abase + 32768 + aoff);
      acc0 = __builtin_amdgcn_mfma_f32_16x16x32_bf16(af0, pf[ks], acc0, 0, 0, 0);
      acc1 = __builtin_amdgcn_mfma_f32_16x16x32_bf16(af1, pf[ks], acc1, 0, 0, 0);
    }
#pragma unroll
    for (int r = 0; r < 4; ++r) {
      int il0 = (lane >> 4) * 4 + r;
      int il1 = il0 + 16;
      float x0 = acc0[r] * rinv[il0];
      float x1 = acc1[r] * rinv[il1];
      x0 = x0 > 0.f ? x0 : (__expf(x0) - 1.f);
      x1 = x1 > 0.f ? x1 : (__expf(x1) - 1.f);
      out[(size_t)(b * NN + rb + il0) * NF + fbw + fl] = x0;
      out[(size_t)(b * NN + rb + il1) * NF + fbw + fl] = x1;
    }
  }
}

extern "C" void kernel_launch(void* const* d_in, const int* in_sizes, int n_in,
                              void* d_out, int out_size, void* d_ws, size_t ws_size,
                              hipStream_t stream) {
  const float* h   = (const float*)d_in[0];
  const float* mz  = (const float*)d_in[1];
  const float* W   = (const float*)d_in[2];
  const float* a   = (const float*)d_in[3];
  const float* w1  = (const float*)d_in[4];
  const float* b1  = (const float*)d_in[5];
  const float* w2  = (const float*)d_in[6];
  const float* b2  = (const float*)d_in[7];
  const int*   adj = (const int*)d_in[8];
  float* out = (float*)d_out;

  unsigned short* WTp = (unsigned short*)d_ws;            // 128KB
  unsigned short* WhP = WTp + 65536;                      // 2MB
  float* wa1 = (float*)(WhP + (size_t)NB * NN * NF);
  float* wa2 = wa1 + 256;
  float* s1g = wa2 + 256;
  float* s2g = s1g + NB * NN;
  unsigned long long* adjm = (unsigned long long*)(s2g + NB * NN);  // 512KB

  prep_kernel<<<dim3(256), dim3(256), 0, stream>>>(W, a, adj, wa1, wa2, WTp,
                                                   adjm);
  wh_kernel<<<dim3(256), dim3(512), 0, stream>>>(h, WTp, wa1, wa2, WhP, s1g, s2g);
  attn_kernel<<<dim3(256), dim3(512), 0, stream>>>(mz, adjm, WhP, w1, b1, w2,
                                                   b2, s1g, s2g, out);
}